// Round 2
// baseline (348723.828 us; speedup 1.0000x reference)
//
#include <hip/hip_runtime.h>
#include <cmath>

#define H_DIM 512
#define GATES 2048
#define SEQ   1024
#define NB    64

// ---------------- concat z = [x | w] : [65536][102] ----------------
__global__ void concat_xw(const float* __restrict__ x, const float* __restrict__ w,
                          float* __restrict__ z, int total) {
    int idx = blockIdx.x * blockDim.x + threadIdx.x;
    if (idx >= total) return;
    int m = idx / 102;
    int f = idx - m * 102;
    z[idx] = (f < 51) ? x[m * 51 + f] : w[m * 51 + (f - 51)];
}

// ---- W_hh [2048][512] -> W8 layout [k/8][h][kk=8][gate=4] floats ----
// value at (k,h,gate) = W_hh[gate*512 + h][k]
__global__ void interleave_whh(const float* __restrict__ W, float* __restrict__ W8) {
    int idx = blockIdx.x * blockDim.x + threadIdx.x;
    if (idx >= H_DIM * H_DIM * 4) return;
    int k    = idx & 511;
    int h    = (idx >> 9) & 511;
    int gate = idx >> 18;
    W8[((((k >> 3) << 9) + h) * 8 + (k & 7)) * 4 + gate] = W[idx];
}

// ---------------- SGEMM: C[m][n] = sum_k A_row(m)[k]*B[n][k] (+b1[n]+b2[n]) ----------------
#define BM 128
#define BN 128
#define BK 8
#define TM 8
#define TN 8

__global__ __launch_bounds__(256) void sgemm_bias(
    const float* __restrict__ A, const float* __restrict__ B, float* __restrict__ C,
    int Mp, int Ncols, int K, int lda, int ldc, int lshift, int t0,
    const float* __restrict__ b1, const float* __restrict__ b2)
{
    __shared__ float As[BK][BM];
    __shared__ float Bs[BK][BN];
    int tid = threadIdx.x;
    int m0 = blockIdx.y * BM;
    int n0 = blockIdx.x * BN;
    int tx = tid & 15, ty = tid >> 4;
    int lrow = tid >> 1;
    int lk4  = (tid & 1) * 4;
    float acc[TM][TN] = {};

    for (int k0 = 0; k0 < K; k0 += BK) {
        {
            int m = m0 + lrow;
            const float* ap = nullptr;
            if (m < Mp) {
                int n = m >> lshift;
                int r = m & ((1 << lshift) - 1);
                long arow = (long)n * SEQ + t0 + r;
                ap = A + arow * (long)lda;
            }
            #pragma unroll
            for (int j = 0; j < 4; ++j) {
                int k = k0 + lk4 + j;
                As[lk4 + j][lrow] = (ap != nullptr && k < K) ? ap[k] : 0.0f;
            }
        }
        {
            int nn = n0 + lrow;
            const float* bp = (nn < Ncols) ? (B + (long)nn * K) : nullptr;
            #pragma unroll
            for (int j = 0; j < 4; ++j) {
                int k = k0 + lk4 + j;
                Bs[lk4 + j][lrow] = (bp != nullptr && k < K) ? bp[k] : 0.0f;
            }
        }
        __syncthreads();
        #pragma unroll
        for (int kk = 0; kk < BK; ++kk) {
            float a[TM], b[TN];
            *(float4*)&a[0] = *(const float4*)&As[kk][ty * TM];
            *(float4*)&a[4] = *(const float4*)&As[kk][ty * TM + 4];
            *(float4*)&b[0] = *(const float4*)&Bs[kk][tx * TN];
            *(float4*)&b[4] = *(const float4*)&Bs[kk][tx * TN + 4];
            #pragma unroll
            for (int i = 0; i < TM; ++i)
                #pragma unroll
                for (int j = 0; j < TN; ++j)
                    acc[i][j] += a[i] * b[j];
        }
        __syncthreads();
    }
    #pragma unroll
    for (int i = 0; i < TM; ++i) {
        int m = m0 + ty * TM + i;
        if (m >= Mp) continue;
        float* crow = C + (long)m * ldc;
        #pragma unroll
        for (int j = 0; j < TN; ++j) {
            int nn = n0 + tx * TN + j;
            if (nn < Ncols) {
                float v = acc[i][j];
                if (b1) v += b1[nn];
                if (b2) v += b2[nn];
                crow[nn] = v;
            }
        }
    }
}

// ---------------- LSTM recurrence: one block (1024 thr) per batch ----------------
// thread = (k-half, h-index). Each computes partial 4-gate dot over 256 k.

#define LD8(R0,R1,R2,R3,R4,R5,R6,R7) \
    R0 = p[0]; R1 = p[1]; R2 = p[2]; R3 = p[3]; \
    R4 = p[4]; R5 = p[5]; R6 = p[6]; R7 = p[7]; p += 8 * H_DIM;

#define FMA8(R0,R1,R2,R3,R4,R5,R6,R7,KO) { \
    float4 h0 = *(const float4*)&h[kb + (KO)]; \
    float4 h1 = *(const float4*)&h[kb + (KO) + 4]; \
    ai += R0.x*h0.x + R1.x*h0.y + R2.x*h0.z + R3.x*h0.w; \
    af += R0.y*h0.x + R1.y*h0.y + R2.y*h0.z + R3.y*h0.w; \
    ag += R0.z*h0.x + R1.z*h0.y + R2.z*h0.z + R3.z*h0.w; \
    ao += R0.w*h0.x + R1.w*h0.y + R2.w*h0.z + R3.w*h0.w; \
    ai += R4.x*h1.x + R5.x*h1.y + R6.x*h1.z + R7.x*h1.w; \
    af += R4.y*h1.x + R5.y*h1.y + R6.y*h1.z + R7.y*h1.w; \
    ag += R4.z*h1.x + R5.z*h1.y + R6.z*h1.z + R7.z*h1.w; \
    ao += R4.w*h1.x + R5.w*h1.y + R6.w*h1.z + R7.w*h1.w; }

__global__ __launch_bounds__(1024) void lstm_rec(
    const float* __restrict__ G,    // [NB][Lseg][2048] gate preacts (incl. biases)
    const float* __restrict__ W8,   // [k/8][h][8][4]
    float* __restrict__ Hs,         // [NB][1024][512]
    float* __restrict__ carry_h, float* __restrict__ carry_c,
    int t0, int Lseg)
{
    const int n   = blockIdx.x;
    const int tid = threadIdx.x;
    const int hh  = tid & 511;
    const int up  = tid >> 9;       // 0: k in [0,256), 1: k in [256,512)
    __shared__ float h[H_DIM];
    __shared__ float part[4][H_DIM];

    float c = 0.0f;
    if (!up) {
        float hv = 0.0f;
        if (t0 != 0) { hv = carry_h[n * H_DIM + hh]; c = carry_c[n * H_DIM + hh]; }
        h[hh] = hv;
    }
    __syncthreads();

    const float* gb = G + (size_t)n * Lseg * GATES;
    float* hsb = Hs + ((size_t)n * SEQ + t0) * H_DIM;
    const int kb = up << 8;                     // 0 or 256
    const float4* wbase = (const float4*)W8 + ((size_t)(kb >> 3) * H_DIM + hh) * 8;
    const int gofs0 = hh + (up ? 1024 : 0);     // i-gate or g-gate
    const int gofs1 = gofs0 + 512;              // f-gate or o-gate

    float gA = gb[gofs0];
    float gB = gb[gofs1];

    for (int t = 0; t < Lseg; ++t) {
        float ai, af, ag, ao;
        if (!up) { ai = gA; af = gB; ag = 0.0f; ao = 0.0f; }
        else     { ag = gA; ao = gB; ai = 0.0f; af = 0.0f; }
        if (t + 1 < Lseg) {      // prefetch next step's gate biases (hides HBM latency)
            const float* gt = gb + (size_t)(t + 1) * GATES;
            gA = gt[gofs0];
            gB = gt[gofs1];
        }

        const float4* p = wbase;
        float4 A0,A1,A2,A3,A4,A5,A6,A7,B0,B1,B2,B3,B4,B5,B6,B7;
        LD8(A0,A1,A2,A3,A4,A5,A6,A7)
        int ko = 0;
        for (int it = 0; it < 15; ++it) {
            LD8(B0,B1,B2,B3,B4,B5,B6,B7)
            FMA8(A0,A1,A2,A3,A4,A5,A6,A7, ko)
            LD8(A0,A1,A2,A3,A4,A5,A6,A7)
            FMA8(B0,B1,B2,B3,B4,B5,B6,B7, ko + 8)
            ko += 16;
        }
        LD8(B0,B1,B2,B3,B4,B5,B6,B7)
        FMA8(A0,A1,A2,A3,A4,A5,A6,A7, 240)
        FMA8(B0,B1,B2,B3,B4,B5,B6,B7, 248)

        if (up) { part[0][hh] = ai; part[1][hh] = af; part[2][hh] = ag; part[3][hh] = ao; }
        __syncthreads();   // partials ready; also: all reads of old h complete
        if (!up) {
            ai += part[0][hh]; af += part[1][hh]; ag += part[2][hh]; ao += part[3][hh];
            float ig = 1.0f / (1.0f + __expf(-ai));
            float fg = 1.0f / (1.0f + __expf(-af));
            float e2 = __expf(2.0f * ag);
            float gg = 1.0f - 2.0f / (e2 + 1.0f);
            float og = 1.0f / (1.0f + __expf(-ao));
            c = fg * c + ig * gg;
            float ec = __expf(2.0f * c);
            float tc = 1.0f - 2.0f / (ec + 1.0f);
            float hn = og * tc;
            h[hh] = hn;
            hsb[(size_t)t * H_DIM + hh] = hn;
        }
        __syncthreads();   // new h visible
    }
    if (!up) {
        carry_h[n * H_DIM + hh] = h[hh];
        carry_c[n * H_DIM + hh] = c;
    }
}

// ---------------- host ----------------
extern "C" void kernel_launch(void* const* d_in, const int* in_sizes, int n_in,
                              void* d_out, int out_size, void* d_ws, size_t ws_size,
                              hipStream_t stream)
{
    const float* x     = (const float*)d_in[0];
    const float* w_in  = (const float*)d_in[1];
    const float* W_ih[3] = { (const float*)d_in[2],  (const float*)d_in[6],  (const float*)d_in[10] };
    const float* W_hh[3] = { (const float*)d_in[3],  (const float*)d_in[7],  (const float*)d_in[11] };
    const float* b_ih[3] = { (const float*)d_in[4],  (const float*)d_in[8],  (const float*)d_in[12] };
    const float* b_hh[3] = { (const float*)d_in[5],  (const float*)d_in[9],  (const float*)d_in[13] };
    const float* W_lin = (const float*)d_in[14];
    const float* b_lin = (const float*)d_in[15];
    float* out = (float*)d_out;

    float* ws = (float*)d_ws;
    size_t off = 0;
    const int M = NB * SEQ;           // 65536
    float* z    = ws + off; off += (size_t)M * 102;
    float* W8[3];
    for (int l = 0; l < 3; ++l) { W8[l] = ws + off; off += (size_t)H_DIM * H_DIM * 4; }
    float* Hs   = ws + off; off += (size_t)M * H_DIM;
    float* ch   = ws + off; off += (size_t)NB * H_DIM;
    float* cc   = ws + off; off += (size_t)NB * H_DIM;
    float* G    = ws + off;

    size_t ws_floats = ws_size / 4;
    size_t avail = (ws_floats > off) ? (ws_floats - off) : 0;
    int Lseg = SEQ;
    while (Lseg > 1 && (size_t)NB * GATES * Lseg > avail) Lseg >>= 1;
    int nseg = SEQ / Lseg;
    int lshift = 0; { int t = Lseg; while (t > 1) { t >>= 1; ++lshift; } }

    {
        int total = M * 102;
        concat_xw<<<(total + 255) / 256, 256, 0, stream>>>(x, w_in, z, total);
    }
    for (int l = 0; l < 3; ++l) {
        int total = H_DIM * H_DIM * 4;
        interleave_whh<<<(total + 255) / 256, 256, 0, stream>>>(W_hh[l], W8[l]);
    }

    for (int l = 0; l < 3; ++l) {
        const float* A = (l == 0) ? z : Hs;
        int K   = (l == 0) ? 102 : H_DIM;
        int lda = K;
        for (int s = 0; s < nseg; ++s) {
            int t0 = s * Lseg;
            int Mp = NB * Lseg;
            dim3 grid((GATES + BN - 1) / BN, (Mp + BM - 1) / BM);
            sgemm_bias<<<grid, 256, 0, stream>>>(A, W_ih[l], G, Mp, GATES, K, lda, GATES,
                                                 lshift, t0, b_ih[l], b_hh[l]);
            lstm_rec<<<NB, 1024, 0, stream>>>(G, W8[l], Hs, ch, cc, t0, Lseg);
        }
    }
    {
        dim3 grid((51 + BN - 1) / BN, (M + BM - 1) / BM);
        sgemm_bias<<<grid, 256, 0, stream>>>(Hs, W_lin, out, M, 51, H_DIM, H_DIM, 51,
                                             10, 0, b_lin, nullptr);
    }
}

// Round 3
// 33272.571 us; speedup vs baseline: 10.4808x; 10.4808x over previous
//
#include <hip/hip_runtime.h>
#include <hip/hip_fp16.h>
#include <cmath>

#define H_DIM 512
#define GATES 2048
#define SEQ   1024
#define NB    64

typedef _Float16 f16;
typedef _Float16 f16x8 __attribute__((ext_vector_type(8)));
typedef float f32x4 __attribute__((ext_vector_type(4)));

// ---------- prep: z16[b][t][128] = f16(cat(x,w)) padded with zeros ----------
__global__ void prep_z(const float* __restrict__ x, const float* __restrict__ w,
                       f16* __restrict__ z16) {
    int idx = blockIdx.x * blockDim.x + threadIdx.x;   // 65536*16
    if (idx >= NB * SEQ * 16) return;
    int m = idx >> 4;
    int k0 = (idx & 15) * 8;
    union { f16 h[8]; int4 v; } u;
    #pragma unroll
    for (int e = 0; e < 8; ++e) {
        int k = k0 + e;
        float v = 0.f;
        if (k < 51)       v = x[m * 51 + k];
        else if (k < 102) v = w[m * 51 + (k - 51)];
        u.h[e] = (f16)v;
    }
    *(int4*)(z16 + (size_t)m * 128 + k0) = u.v;
}

// ---------- generic fp32 -> f16 with row/col zero padding ----------
__global__ void conv16(const float* __restrict__ src, f16* __restrict__ dst,
                       int Rs, int Cs, int Rd, int Cp) {
    int idx = blockIdx.x * blockDim.x + threadIdx.x;
    if (idx >= Rd * Cp) return;
    int r = idx / Cp, c = idx - r * Cp;
    float v = (r < Rs && c < Cs) ? src[r * Cs + c] : 0.f;
    dst[idx] = (f16)v;
}

// ---------- projection GEMM (f16 MFMA, all-global) ----------
// D[row=M][col=(T,b)] = A[row][k] * B[b][T][k]
// MODE 0: store Gt[tl][2048][64] += biases   MODE 1: store out[b][T][51] + bias1
template<int KT, int MODE>
__global__ __launch_bounds__(256) void proj_gemm(
    const f16* __restrict__ A, const f16* __restrict__ B, float* __restrict__ C,
    const float* __restrict__ bias1, const float* __restrict__ bias2, int t0)
{
    const int my = blockIdx.x;
    const int tl = blockIdx.y;
    const int T  = t0 + tl;
    const int tid = threadIdx.x;
    const int wv = tid >> 6, l = tid & 63;
    const int K = KT * 32;
    const int mrow0 = my * 64 + wv * 16;
    int4 a[KT];
    {
        const f16* ap = A + (size_t)(mrow0 + (l & 15)) * K + ((l >> 4) * 8);
        #pragma unroll
        for (int kt = 0; kt < KT; ++kt) a[kt] = *(const int4*)(ap + kt * 32);
    }
    #pragma unroll
    for (int nt = 0; nt < 4; ++nt) {
        const int bcol = nt * 16 + (l & 15);
        const f16* bp = B + ((size_t)bcol * SEQ + T) * K + ((l >> 4) * 8);
        f32x4 acc = {0.f, 0.f, 0.f, 0.f};
        #pragma unroll
        for (int kt = 0; kt < KT; ++kt) {
            int4 bq = *(const int4*)(bp + kt * 32);
            acc = __builtin_amdgcn_mfma_f32_16x16x32_f16(
                __builtin_bit_cast(f16x8, a[kt]), __builtin_bit_cast(f16x8, bq), acc, 0, 0, 0);
        }
        #pragma unroll
        for (int e = 0; e < 4; ++e) {
            int row = mrow0 + (l >> 4) * 4 + e;
            if (MODE == 0) {
                C[((size_t)tl * GATES + row) * 64 + bcol] = acc[e] + bias1[row] + bias2[row];
            } else {
                if (row < 51)
                    C[((size_t)bcol * SEQ + T) * 51 + row] = acc[e] + bias1[row];
            }
        }
    }
}

// ---------- LSTM recurrence: 64 blocks, W in registers, grid barrier ----------
__global__ __launch_bounds__(512) void lstm_rec(
    const float* __restrict__ Gt,   // [Lseg][2048][64]
    const f16* __restrict__ Whh16,  // [2048][512]
    f16* __restrict__ Hs16,         // [64][1024][512]
    f16* __restrict__ Ht,           // [2][64][512]
    float* __restrict__ cst,        // [64][512]
    int* __restrict__ barr,         // [64] per-layer arrival slots
    int t0, int Lseg)
{
    const int bid = blockIdx.x;          // 64
    const int tid = threadIdx.x;         // 512
    const int wv = tid >> 6;             // 0..7
    const int l = tid & 63;
    const int mtile = wv & 1, ntile = wv >> 1;
    const int j0 = bid * 8;
    const int aj = wv;                   // activation role: j offset
    const int ab = l;                    // activation role: batch
    __shared__ float gl[4 * 8 * 64];
    __shared__ f16 hl[8 * 64];

    // persistent A-fragments (W slice, 32 rows x 512 k)
    const int rl = l & 15;
    const int gate = mtile * 2 + (rl >> 3);
    const int grow = gate * 512 + j0 + (rl & 7);
    int4 a[16];
    {
        const f16* ap = Whh16 + (size_t)grow * 512 + ((l >> 4) * 8);
        #pragma unroll
        for (int kt = 0; kt < 16; ++kt) a[kt] = *(const int4*)(ap + kt * 32);
    }
    float c = 0.f;
    if (t0 > 0) c = cst[(size_t)ab * 512 + j0 + aj];

    int cur = 0;
    for (int t = 0; t < Lseg; ++t) {
        const int T = t0 + t;
        // gate preact prefetch (coalesced 256B rows)
        const float* gp = Gt + (size_t)t * GATES * 64;
        float g0 = gp[(size_t)(0 * 512 + j0 + aj) * 64 + ab];
        float g1 = gp[(size_t)(1 * 512 + j0 + aj) * 64 + ab];
        float g2 = gp[(size_t)(2 * 512 + j0 + aj) * 64 + ab];
        float g3 = gp[(size_t)(3 * 512 + j0 + aj) * 64 + ab];
        // B-fragments direct from Ht[cur], then MFMA
        f32x4 acc = {0.f, 0.f, 0.f, 0.f};
        const f16* bp = Ht + (size_t)cur * NB * 512 + (size_t)(ntile * 16 + rl) * 512 + ((l >> 4) * 8);
        #pragma unroll
        for (int kt = 0; kt < 16; ++kt) {
            int4 bq = *(const int4*)(bp + kt * 32);
            acc = __builtin_amdgcn_mfma_f32_16x16x32_f16(
                __builtin_bit_cast(f16x8, a[kt]), __builtin_bit_cast(f16x8, bq), acc, 0, 0, 0);
        }
        // exchange gate partials to LDS
        #pragma unroll
        for (int e = 0; e < 4; ++e) {
            int rloc = (l >> 4) * 4 + e;
            int g = mtile * 2 + (rloc >> 3);
            int jj = rloc & 7;
            gl[((g * 8 + jj) << 6) + (ntile * 16 + rl)] = acc[e];
        }
        __syncthreads();
        // activations: thread = (aj, ab)
        float ai = g0 + gl[((0 * 8 + aj) << 6) + ab];
        float af = g1 + gl[((1 * 8 + aj) << 6) + ab];
        float ag = g2 + gl[((2 * 8 + aj) << 6) + ab];
        float ao = g3 + gl[((3 * 8 + aj) << 6) + ab];
        float ig = 1.f / (1.f + __expf(-ai));
        float fg = 1.f / (1.f + __expf(-af));
        float gg = 1.f - 2.f / (__expf(2.f * ag) + 1.f);
        float og = 1.f / (1.f + __expf(-ao));
        c = fg * c + ig * gg;
        float hn = og * (1.f - 2.f / (__expf(2.f * c) + 1.f));
        hl[(aj << 6) + ab] = (f16)hn;
        __syncthreads();
        // pack new h: thread b stores 8 f16 (16B) to Ht[cur^1] and Hs16
        if (tid < 64) {
            union { f16 h[8]; int4 v; } u;
            #pragma unroll
            for (int jj = 0; jj < 8; ++jj) u.h[jj] = hl[(jj << 6) + tid];
            *(int4*)(Ht + (size_t)(cur ^ 1) * NB * 512 + (size_t)tid * 512 + j0) = u.v;
            *(int4*)(Hs16 + ((size_t)tid * SEQ + T) * 512 + j0) = u.v;
        }
        __syncthreads();   // stores drained (vmcnt) before signaling
        if (tid == 0) {
            __threadfence();  // write back L2 (cross-XCD visibility)
            __hip_atomic_store(&barr[bid], T + 1, __ATOMIC_RELEASE, __HIP_MEMORY_SCOPE_AGENT);
        }
        if (wv == 0) {
            while (__hip_atomic_load(&barr[l], __ATOMIC_ACQUIRE, __HIP_MEMORY_SCOPE_AGENT) < T + 1)
                __builtin_amdgcn_s_sleep(2);
        }
        __syncthreads();
        cur ^= 1;
    }
    cst[(size_t)ab * 512 + j0 + aj] = c;
}

// ---------- host ----------
extern "C" void kernel_launch(void* const* d_in, const int* in_sizes, int n_in,
                              void* d_out, int out_size, void* d_ws, size_t ws_size,
                              hipStream_t stream)
{
    const float* x     = (const float*)d_in[0];
    const float* w_in  = (const float*)d_in[1];
    const float* W_ih[3] = { (const float*)d_in[2],  (const float*)d_in[6],  (const float*)d_in[10] };
    const float* W_hh[3] = { (const float*)d_in[3],  (const float*)d_in[7],  (const float*)d_in[11] };
    const float* b_ih[3] = { (const float*)d_in[4],  (const float*)d_in[8],  (const float*)d_in[12] };
    const float* b_hh[3] = { (const float*)d_in[5],  (const float*)d_in[9],  (const float*)d_in[13] };
    const float* W_lin = (const float*)d_in[14];
    const float* b_lin = (const float*)d_in[15];
    float* out = (float*)d_out;

    char* ws = (char*)d_ws;
    size_t off = 0;
    auto alloc = [&](size_t bytes) { char* p = ws + off; off += (bytes + 255) & ~(size_t)255; return p; };

    f16* z16    = (f16*)alloc((size_t)NB * SEQ * 128 * 2);
    f16* wih16[3];
    wih16[0] = (f16*)alloc((size_t)GATES * 128 * 2);
    wih16[1] = (f16*)alloc((size_t)GATES * 512 * 2);
    wih16[2] = (f16*)alloc((size_t)GATES * 512 * 2);
    f16* whh16[3];
    for (int i = 0; i < 3; ++i) whh16[i] = (f16*)alloc((size_t)GATES * 512 * 2);
    f16* wlin16 = (f16*)alloc((size_t)64 * 512 * 2);
    f16* Hs16   = (f16*)alloc((size_t)NB * SEQ * 512 * 2);
    f16* Ht     = (f16*)alloc((size_t)2 * NB * 512 * 2);
    float* cst  = (float*)alloc((size_t)NB * 512 * 4);
    int* barr   = (int*)alloc(3 * 64 * 4);
    size_t gt_off = off;
    float* Gt   = (float*)(ws + gt_off);

    size_t avail = (ws_size > gt_off) ? ws_size - gt_off : 0;
    int Lseg = SEQ;
    while (Lseg > 16 && (size_t)Lseg * GATES * 64 * 4 > avail) Lseg >>= 1;
    int nseg = SEQ / Lseg;

    // prep
    prep_z<<<(NB * SEQ * 16 + 255) / 256, 256, 0, stream>>>(x, w_in, z16);
    conv16<<<(GATES * 128 + 255) / 256, 256, 0, stream>>>(W_ih[0], wih16[0], GATES, 102, GATES, 128);
    conv16<<<(GATES * 512 + 255) / 256, 256, 0, stream>>>(W_ih[1], wih16[1], GATES, 512, GATES, 512);
    conv16<<<(GATES * 512 + 255) / 256, 256, 0, stream>>>(W_ih[2], wih16[2], GATES, 512, GATES, 512);
    for (int i = 0; i < 3; ++i)
        conv16<<<(GATES * 512 + 255) / 256, 256, 0, stream>>>(W_hh[i], whh16[i], GATES, 512, GATES, 512);
    conv16<<<(64 * 512 + 255) / 256, 256, 0, stream>>>(W_lin, wlin16, 51, 512, 64, 512);
    hipMemsetAsync(barr, 0, 3 * 64 * 4, stream);

    for (int lyr = 0; lyr < 3; ++lyr) {
        hipMemsetAsync(Ht, 0, (size_t)2 * NB * 512 * 2, stream);
        for (int s = 0; s < nseg; ++s) {
            int t0 = s * Lseg;
            dim3 pg(GATES / 64, Lseg);
            if (lyr == 0)
                proj_gemm<4, 0><<<pg, 256, 0, stream>>>(wih16[0], z16, Gt, b_ih[0], b_hh[0], t0);
            else
                proj_gemm<16, 0><<<pg, 256, 0, stream>>>(wih16[lyr], Hs16, Gt, b_ih[lyr], b_hh[lyr], t0);
            lstm_rec<<<64, 512, 0, stream>>>(Gt, whh16[lyr], Hs16, Ht, cst, barr + lyr * 64, t0, Lseg);
        }
    }
    // final linear
    {
        dim3 pg(1, SEQ);
        proj_gemm<16, 1><<<pg, 256, 0, stream>>>(wlin16, Hs16, out, b_lin, b_lin, 0);
    }
}

// Round 4
// 24945.409 us; speedup vs baseline: 13.9795x; 1.3338x over previous
//
#include <hip/hip_runtime.h>
#include <hip/hip_fp16.h>
#include <cmath>

#define H_DIM 512
#define GATES 2048
#define SEQ   1024
#define NB    64

typedef _Float16 f16;
typedef _Float16 f16x8 __attribute__((ext_vector_type(8)));
typedef float f32x4 __attribute__((ext_vector_type(4)));

__device__ __forceinline__ f32x4 MFMA(int4 a, int4 b, f32x4 acc) {
    return __builtin_amdgcn_mfma_f32_16x16x32_f16(
        __builtin_bit_cast(f16x8, a), __builtin_bit_cast(f16x8, b), acc, 0, 0, 0);
}

// ---------- prep: z16[b][t][128] = f16(cat(x,w)) padded with zeros ----------
__global__ void prep_z(const float* __restrict__ x, const float* __restrict__ w,
                       f16* __restrict__ z16) {
    int idx = blockIdx.x * blockDim.x + threadIdx.x;   // 65536*16
    if (idx >= NB * SEQ * 16) return;
    int m = idx >> 4;
    int k0 = (idx & 15) * 8;
    union { f16 h[8]; int4 v; } u;
    #pragma unroll
    for (int e = 0; e < 8; ++e) {
        int k = k0 + e;
        float v = 0.f;
        if (k < 51)       v = x[m * 51 + k];
        else if (k < 102) v = w[m * 51 + (k - 51)];
        u.h[e] = (f16)v;
    }
    *(int4*)(z16 + (size_t)m * 128 + k0) = u.v;
}

// ---------- generic fp32 -> f16 with row/col zero padding ----------
__global__ void conv16(const float* __restrict__ src, f16* __restrict__ dst,
                       int Rs, int Cs, int Rd, int Cp) {
    int idx = blockIdx.x * blockDim.x + threadIdx.x;
    if (idx >= Rd * Cp) return;
    int r = idx / Cp, c = idx - r * Cp;
    float v = (r < Rs && c < Cs) ? src[r * Cs + c] : 0.f;
    dst[idx] = (f16)v;
}

// ---------- fused 3-layer diagonal-pipelined LSTM ----------
// 192 blocks: layer = bid>>6 (0..2), sub = bid&63 owns h-rows [sub*8, sub*8+8)
// of its layer (32 gate rows). W_ih and W_hh slices live in registers as MFMA
// A-fragments. Per diagonal d: layer L computes t = d - L; needs h_prev(t)
// (published at d-1 by layer L-1) and h_own(t-1) (published at d-1).
__global__ __launch_bounds__(512, 2) void lstm_fused(
    const f16* __restrict__ z16,     // [64][1024][128]
    const f16* __restrict__ wih0, const f16* __restrict__ wih1, const f16* __restrict__ wih2,
    const f16* __restrict__ whh0, const f16* __restrict__ whh1, const f16* __restrict__ whh2,
    const float* __restrict__ bih0, const float* __restrict__ bhh0,
    const float* __restrict__ bih1, const float* __restrict__ bhh1,
    const float* __restrict__ bih2, const float* __restrict__ bhh2,
    f16* __restrict__ Ht,            // [3][2][64][512] parity ping-pong
    f16* __restrict__ Hs16,          // [64][1024][512] layer-3 history
    int* __restrict__ barr)          // [192]
{
    const int bid   = blockIdx.x;
    const int layer = bid >> 6;
    const int sub   = bid & 63;
    const int tid   = threadIdx.x;
    const int wv    = tid >> 6;          // 0..7
    const int l     = tid & 63;
    const int rl    = l & 15;
    const int kq    = l >> 4;            // 0..3
    const int mtile = wv & 1, ntile = wv >> 1;
    const int j0    = sub * 8;
    const int aj    = wv, ab = l;        // activation role

    __shared__ float gl[4 * 8 * 64];
    __shared__ f16 hl[8 * 64];

    const f16* wih = (layer == 0) ? wih0 : ((layer == 1) ? wih1 : wih2);
    const f16* whh = (layer == 0) ? whh0 : ((layer == 1) ? whh1 : whh2);
    const float* bi = (layer == 0) ? bih0 : ((layer == 1) ? bih1 : bih2);
    const float* bh = (layer == 0) ? bhh0 : ((layer == 1) ? bhh1 : bhh2);

    const int gate = mtile * 2 + (rl >> 3);
    const int grow = gate * 512 + j0 + (rl & 7);

    // persistent A-fragments
    int4 aW[16];
    {
        const f16* p = whh + (size_t)grow * 512 + kq * 8;
        #pragma unroll
        for (int kt = 0; kt < 16; ++kt) aW[kt] = *(const int4*)(p + kt * 32);
    }
    int4 aI[16];
    if (layer == 0) {
        const f16* p = wih + (size_t)grow * 128 + kq * 8;
        #pragma unroll
        for (int kt = 0; kt < 4; ++kt) aI[kt] = *(const int4*)(p + kt * 32);
    } else {
        const f16* p = wih + (size_t)grow * 512 + kq * 8;
        #pragma unroll
        for (int kt = 0; kt < 16; ++kt) aI[kt] = *(const int4*)(p + kt * 32);
    }
    // per-thread gate biases (row j0+aj, all 4 gates)
    const float bI = bi[j0 + aj]        + bh[j0 + aj];
    const float bF = bi[512 + j0 + aj]  + bh[512 + j0 + aj];
    const float bG = bi[1024 + j0 + aj] + bh[1024 + j0 + aj];
    const float bO = bi[1536 + j0 + aj] + bh[1536 + j0 + aj];
    float c = 0.f;

    const int TOTAL = SEQ + 2;           // 1026 diagonals
    for (int d = 0; d < TOTAL; ++d) {
        const int t = d - layer;
        const bool active = (t >= 0) && (t < SEQ);
        if (active) {
            const int parO = t & 1;          // publish parity for h(t)
            const int parI = parO ^ 1;       // own h(t-1) parity
            const int brow = ntile * 16 + rl;
            f32x4 accI = {0.f, 0.f, 0.f, 0.f}, accW = {0.f, 0.f, 0.f, 0.f};
            const f16* hO = Ht + (((size_t)layer * 2 + parI) * NB + brow) * 512 + kq * 8;
            if (layer == 0) {
                const f16* zB = z16 + ((size_t)brow * SEQ + t) * 128 + kq * 8;
                #pragma unroll
                for (int kt = 0; kt < 4; ++kt)
                    accI = MFMA(aI[kt], *(const int4*)(zB + kt * 32), accI);
                #pragma unroll
                for (int kt = 0; kt < 16; ++kt)
                    accW = MFMA(aW[kt], *(const int4*)(hO + kt * 32), accW);
            } else {
                const f16* hP = Ht + (((size_t)(layer - 1) * 2 + parO) * NB + brow) * 512 + kq * 8;
                #pragma unroll
                for (int kt = 0; kt < 16; ++kt) {
                    int4 b1 = *(const int4*)(hP + kt * 32);
                    int4 b2 = *(const int4*)(hO + kt * 32);
                    accI = MFMA(aI[kt], b1, accI);
                    accW = MFMA(aW[kt], b2, accW);
                }
            }
            // exchange gate partials (C layout: row=(kq)*4+e within tile, col=brow)
            #pragma unroll
            for (int e = 0; e < 4; ++e) {
                int rloc = kq * 4 + e;
                int g = mtile * 2 + (rloc >> 3);
                int jj = rloc & 7;
                gl[((g * 8 + jj) << 6) + (ntile * 16 + rl)] = accI[e] + accW[e];
            }
        }
        __syncthreads();
        if (active) {
            float ai = bI + gl[((0 * 8 + aj) << 6) + ab];
            float af = bF + gl[((1 * 8 + aj) << 6) + ab];
            float ag = bG + gl[((2 * 8 + aj) << 6) + ab];
            float ao = bO + gl[((3 * 8 + aj) << 6) + ab];
            float ig = 1.f / (1.f + __expf(-ai));
            float fg = 1.f / (1.f + __expf(-af));
            float gg = 1.f - 2.f / (__expf(2.f * ag) + 1.f);
            float og = 1.f / (1.f + __expf(-ao));
            c = fg * c + ig * gg;
            float hn = og * (1.f - 2.f / (__expf(2.f * c) + 1.f));
            hl[(aj << 6) + ab] = (f16)hn;
        }
        __syncthreads();
        if (active && tid < 64) {
            union { f16 h[8]; int4 v; } u;
            #pragma unroll
            for (int jj = 0; jj < 8; ++jj) u.h[jj] = hl[(jj << 6) + tid];
            *(int4*)(Ht + (((size_t)layer * 2 + (t & 1)) * NB + tid) * 512 + j0) = u.v;
            if (layer == 2)
                *(int4*)(Hs16 + ((size_t)tid * SEQ + t) * 512 + j0) = u.v;
        }
        __syncthreads();   // stores drained before signaling
        if (tid == 0) {
            __threadfence();
            __hip_atomic_store(&barr[bid], d + 1, __ATOMIC_RELEASE, __HIP_MEMORY_SCOPE_AGENT);
        }
        if (wv == 0) {
            #pragma unroll
            for (int q = 0; q < 3; ++q) {
                while (__hip_atomic_load(&barr[q * 64 + l], __ATOMIC_ACQUIRE,
                                         __HIP_MEMORY_SCOPE_AGENT) < d + 1)
                    __builtin_amdgcn_s_sleep(2);
            }
        }
        __syncthreads();
    }
}

// ---------- final linear: out[b][T][51] = Wlin @ h3 + b ----------
__global__ __launch_bounds__(256) void final_gemm(
    const f16* __restrict__ A, const f16* __restrict__ B, float* __restrict__ C,
    const float* __restrict__ bias1)
{
    const int T  = blockIdx.x;
    const int tid = threadIdx.x;
    const int wv = tid >> 6, l = tid & 63;
    const int K = 512;
    const int mrow0 = wv * 16;
    int4 a[16];
    {
        const f16* ap = A + (size_t)(mrow0 + (l & 15)) * K + ((l >> 4) * 8);
        #pragma unroll
        for (int kt = 0; kt < 16; ++kt) a[kt] = *(const int4*)(ap + kt * 32);
    }
    #pragma unroll
    for (int nt = 0; nt < 4; ++nt) {
        const int bcol = nt * 16 + (l & 15);
        const f16* bp = B + ((size_t)bcol * SEQ + T) * K + ((l >> 4) * 8);
        f32x4 acc = {0.f, 0.f, 0.f, 0.f};
        #pragma unroll
        for (int kt = 0; kt < 16; ++kt)
            acc = MFMA(a[kt], *(const int4*)(bp + kt * 32), acc);
        #pragma unroll
        for (int e = 0; e < 4; ++e) {
            int row = mrow0 + (l >> 4) * 4 + e;
            if (row < 51)
                C[((size_t)bcol * SEQ + T) * 51 + row] = acc[e] + bias1[row];
        }
    }
}

// ---------- host ----------
extern "C" void kernel_launch(void* const* d_in, const int* in_sizes, int n_in,
                              void* d_out, int out_size, void* d_ws, size_t ws_size,
                              hipStream_t stream)
{
    const float* x     = (const float*)d_in[0];
    const float* w_in  = (const float*)d_in[1];
    const float* W_ih[3] = { (const float*)d_in[2],  (const float*)d_in[6],  (const float*)d_in[10] };
    const float* W_hh[3] = { (const float*)d_in[3],  (const float*)d_in[7],  (const float*)d_in[11] };
    const float* b_ih[3] = { (const float*)d_in[4],  (const float*)d_in[8],  (const float*)d_in[12] };
    const float* b_hh[3] = { (const float*)d_in[5],  (const float*)d_in[9],  (const float*)d_in[13] };
    const float* W_lin = (const float*)d_in[14];
    const float* b_lin = (const float*)d_in[15];
    float* out = (float*)d_out;

    char* ws = (char*)d_ws;
    size_t off = 0;
    auto alloc = [&](size_t bytes) { char* p = ws + off; off += (bytes + 255) & ~(size_t)255; return p; };

    f16* z16 = (f16*)alloc((size_t)NB * SEQ * 128 * 2);
    f16* wih16[3];
    wih16[0] = (f16*)alloc((size_t)GATES * 128 * 2);
    wih16[1] = (f16*)alloc((size_t)GATES * 512 * 2);
    wih16[2] = (f16*)alloc((size_t)GATES * 512 * 2);
    f16* whh16[3];
    for (int i = 0; i < 3; ++i) whh16[i] = (f16*)alloc((size_t)GATES * 512 * 2);
    f16* wlin16 = (f16*)alloc((size_t)64 * 512 * 2);
    f16* Hs16   = (f16*)alloc((size_t)NB * SEQ * 512 * 2);
    f16* Ht     = (f16*)alloc((size_t)3 * 2 * NB * 512 * 2);
    int* barr   = (int*)alloc(192 * 4);

    // prep + conversions
    prep_z<<<(NB * SEQ * 16 + 255) / 256, 256, 0, stream>>>(x, w_in, z16);
    conv16<<<(GATES * 128 + 255) / 256, 256, 0, stream>>>(W_ih[0], wih16[0], GATES, 102, GATES, 128);
    conv16<<<(GATES * 512 + 255) / 256, 256, 0, stream>>>(W_ih[1], wih16[1], GATES, 512, GATES, 512);
    conv16<<<(GATES * 512 + 255) / 256, 256, 0, stream>>>(W_ih[2], wih16[2], GATES, 512, GATES, 512);
    for (int i = 0; i < 3; ++i)
        conv16<<<(GATES * 512 + 255) / 256, 256, 0, stream>>>(W_hh[i], whh16[i], GATES, 512, GATES, 512);
    conv16<<<(64 * 512 + 255) / 256, 256, 0, stream>>>(W_lin, wlin16, 51, 512, 64, 512);
    hipMemsetAsync(Ht, 0, (size_t)3 * 2 * NB * 512 * 2, stream);
    hipMemsetAsync(barr, 0, 192 * 4, stream);

    // fused 3-layer recurrence (single dispatch, 192 co-resident blocks)
    lstm_fused<<<192, 512, 0, stream>>>(
        z16, wih16[0], wih16[1], wih16[2], whh16[0], whh16[1], whh16[2],
        b_ih[0], b_hh[0], b_ih[1], b_hh[1], b_ih[2], b_hh[2],
        Ht, Hs16, barr);

    // final linear
    final_gemm<<<SEQ, 256, 0, stream>>>(wlin16, Hs16, out, b_lin);
}

// Round 7
// 18441.072 us; speedup vs baseline: 18.9102x; 1.3527x over previous
//
#include <hip/hip_runtime.h>
#include <hip/hip_fp16.h>
#include <cmath>

#define H_DIM 512
#define GATES 2048
#define SEQ   1024
#define NB    64

typedef _Float16 f16;
typedef _Float16 f16x8 __attribute__((ext_vector_type(8)));
typedef float f32x4 __attribute__((ext_vector_type(4)));

__device__ __forceinline__ f32x4 MFMA(int4 a, int4 b, f32x4 acc) {
    return __builtin_amdgcn_mfma_f32_16x16x32_f16(
        __builtin_bit_cast(f16x8, a), __builtin_bit_cast(f16x8, b), acc, 0, 0, 0);
}

// ---------- prep: z16[b][t][128] = f16(cat(x,w)) padded with zeros ----------
__global__ void prep_z(const float* __restrict__ x, const float* __restrict__ w,
                       f16* __restrict__ z16) {
    int idx = blockIdx.x * blockDim.x + threadIdx.x;   // 65536*16
    if (idx >= NB * SEQ * 16) return;
    int m = idx >> 4;
    int k0 = (idx & 15) * 8;
    union { f16 h[8]; int4 v; } u;
    #pragma unroll
    for (int e = 0; e < 8; ++e) {
        int k = k0 + e;
        float v = 0.f;
        if (k < 51)       v = x[m * 51 + k];
        else if (k < 102) v = w[m * 51 + (k - 51)];
        u.h[e] = (f16)v;
    }
    *(int4*)(z16 + (size_t)m * 128 + k0) = u.v;
}

// ---------- generic fp32 -> f16 with row/col zero padding ----------
__global__ void conv16(const float* __restrict__ src, f16* __restrict__ dst,
                       int Rs, int Cs, int Rd, int Cp) {
    int idx = blockIdx.x * blockDim.x + threadIdx.x;
    if (idx >= Rd * Cp) return;
    int r = idx / Cp, c = idx - r * Cp;
    float v = (r < Rs && c < Cs) ? src[r * Cs + c] : 0.f;
    dst[idx] = (f16)v;
}

// ---------- fused 3-layer diagonal-pipelined LSTM ----------
// 192 blocks: layer = bid>>6, sub = bid&63 owns h-rows [sub*8, sub*8+8).
// Poll with RELAXED agent loads (coherent, no per-poll L2 inv); ONE acquire
// fence per block per diagonal. Spin is BOUNDED (fail-safe): on timeout we
// proceed (wrong results instead of a hung container).
#define GLS 68   // gl row stride: 4*GLS % 32 == 16 -> exact 2-way bank aliasing (free)

__global__ __launch_bounds__(512, 2) void lstm_fused(
    const f16* __restrict__ z16,     // [64][1024][128]
    const f16* __restrict__ wih0, const f16* __restrict__ wih1, const f16* __restrict__ wih2,
    const f16* __restrict__ whh0, const f16* __restrict__ whh1, const f16* __restrict__ whh2,
    const float* __restrict__ bih0, const float* __restrict__ bhh0,
    const float* __restrict__ bih1, const float* __restrict__ bhh1,
    const float* __restrict__ bih2, const float* __restrict__ bhh2,
    f16* __restrict__ Ht,            // [3][2][64][512] parity ping-pong
    f16* __restrict__ Hs16,          // [64][1024][512] layer-3 history
    int* __restrict__ barr)          // [192]
{
    const int bid   = blockIdx.x;
    const int layer = bid >> 6;
    const int sub   = bid & 63;
    const int tid   = threadIdx.x;
    const int wv    = tid >> 6;          // 0..7
    const int l     = tid & 63;
    const int rl    = l & 15;
    const int kq    = l >> 4;            // 0..3
    const int mtile = wv & 1, ntile = wv >> 1;
    const int j0    = sub * 8;
    const int aj    = wv, ab = l;        // activation role

    __shared__ float gl[32 * GLS];
    __shared__ f16 hl[8 * 64];

    const f16* wih = (layer == 0) ? wih0 : ((layer == 1) ? wih1 : wih2);
    const f16* whh = (layer == 0) ? whh0 : ((layer == 1) ? whh1 : whh2);
    const float* bi = (layer == 0) ? bih0 : ((layer == 1) ? bih1 : bih2);
    const float* bh = (layer == 0) ? bhh0 : ((layer == 1) ? bhh1 : bhh2);

    const int gate = mtile * 2 + (rl >> 3);
    const int grow = gate * 512 + j0 + (rl & 7);
    const int brow = ntile * 16 + rl;

    // persistent A-fragments
    int4 aW[16];
    {
        const f16* p = whh + (size_t)grow * 512 + kq * 8;
        #pragma unroll
        for (int kt = 0; kt < 16; ++kt) aW[kt] = *(const int4*)(p + kt * 32);
    }
    int4 aI[16];
    if (layer == 0) {
        const f16* p = wih + (size_t)grow * 128 + kq * 8;
        #pragma unroll
        for (int kt = 0; kt < 4; ++kt) aI[kt] = *(const int4*)(p + kt * 32);
    } else {
        const f16* p = wih + (size_t)grow * 512 + kq * 8;
        #pragma unroll
        for (int kt = 0; kt < 16; ++kt) aI[kt] = *(const int4*)(p + kt * 32);
    }
    // per-thread gate biases
    const float bI = bi[j0 + aj]        + bh[j0 + aj];
    const float bF = bi[512 + j0 + aj]  + bh[512 + j0 + aj];
    const float bG = bi[1024 + j0 + aj] + bh[1024 + j0 + aj];
    const float bO = bi[1536 + j0 + aj] + bh[1536 + j0 + aj];
    float c = 0.f;

    // layer-0 z prefetch registers (t=0)
    int4 zreg[4];
    if (layer == 0) {
        const f16* zB = z16 + ((size_t)brow * SEQ + 0) * 128 + kq * 8;
        #pragma unroll
        for (int kt = 0; kt < 4; ++kt) zreg[kt] = *(const int4*)(zB + kt * 32);
    }

    const int TOTAL = SEQ + 2;           // 1026 diagonals
    for (int d = 0; d < TOTAL; ++d) {
        const int t = d - layer;
        const bool active = (t >= 0) && (t < SEQ);
        if (active) {
            const int parO = t & 1;          // publish parity for h(t)
            const int parI = parO ^ 1;       // own h(t-1) parity
            f32x4 accI = {0.f, 0.f, 0.f, 0.f}, accW = {0.f, 0.f, 0.f, 0.f};
            const f16* hO = Ht + (((size_t)layer * 2 + parI) * NB + brow) * 512 + kq * 8;
            if (layer == 0) {
                #pragma unroll
                for (int kt = 0; kt < 4; ++kt)
                    accI = MFMA(aI[kt], zreg[kt], accI);
                #pragma unroll
                for (int kt = 0; kt < 16; ++kt)
                    accW = MFMA(aW[kt], *(const int4*)(hO + kt * 32), accW);
                if (t + 1 < SEQ) {           // prefetch next z before the barrier
                    const f16* zB = z16 + ((size_t)brow * SEQ + (t + 1)) * 128 + kq * 8;
                    #pragma unroll
                    for (int kt = 0; kt < 4; ++kt) zreg[kt] = *(const int4*)(zB + kt * 32);
                }
            } else {
                const f16* hP = Ht + (((size_t)(layer - 1) * 2 + parO) * NB + brow) * 512 + kq * 8;
                #pragma unroll
                for (int kt = 0; kt < 16; ++kt) {
                    int4 b1 = *(const int4*)(hP + kt * 32);
                    int4 b2 = *(const int4*)(hO + kt * 32);
                    accI = MFMA(aI[kt], b1, accI);
                    accW = MFMA(aW[kt], b2, accW);
                }
            }
            // exchange gate partials (padded rows: exact 2-way bank aliasing)
            #pragma unroll
            for (int e = 0; e < 4; ++e) {
                int rloc = kq * 4 + e;
                int g = mtile * 2 + (rloc >> 3);
                int jj = rloc & 7;
                gl[(g * 8 + jj) * GLS + brow] = accI[e] + accW[e];
            }
        }
        __syncthreads();
        if (active) {
            float ai = bI + gl[(0 * 8 + aj) * GLS + ab];
            float af = bF + gl[(1 * 8 + aj) * GLS + ab];
            float ag = bG + gl[(2 * 8 + aj) * GLS + ab];
            float ao = bO + gl[(3 * 8 + aj) * GLS + ab];
            float ig = 1.f / (1.f + __expf(-ai));
            float fg = 1.f / (1.f + __expf(-af));
            float gg = 1.f - 2.f / (__expf(2.f * ag) + 1.f);
            float og = 1.f / (1.f + __expf(-ao));
            c = fg * c + ig * gg;
            float hn = og * (1.f - 2.f / (__expf(2.f * c) + 1.f));
            hl[(aj << 6) + ab] = (f16)hn;
        }
        __syncthreads();
        if (active && tid < 64) {
            union { f16 h[8]; int4 v; } u;
            #pragma unroll
            for (int jj = 0; jj < 8; ++jj) u.h[jj] = hl[(jj << 6) + tid];
            *(int4*)(Ht + (((size_t)layer * 2 + (t & 1)) * NB + tid) * 512 + j0) = u.v;
            if (layer == 2)
                *(int4*)(Hs16 + ((size_t)tid * SEQ + t) * 512 + j0) = u.v;
        }
        __syncthreads();   // stores drained (vmcnt) before signaling
        if (tid == 0) {
            // RELEASE at agent scope: writes back dirty L2 then publishes arrival
            __hip_atomic_store(&barr[bid], d + 1, __ATOMIC_RELEASE, __HIP_MEMORY_SCOPE_AGENT);
        }
        if (wv == 0) {
            // RELAXED polls: coherent loads, NO buffer_inv per poll.
            // Bounded spin (~200k iters ≈ 10 ms): on timeout proceed anyway so a
            // protocol bug shows up as absmax failure, never a hung container.
            #pragma unroll
            for (int q = 0; q < 3; ++q) {
                int spins = 0;
                while (__hip_atomic_load(&barr[q * 64 + l], __ATOMIC_RELAXED,
                                         __HIP_MEMORY_SCOPE_AGENT) < d + 1) {
                    __builtin_amdgcn_s_sleep(2);
                    if (++spins > 200000) break;
                }
            }
            // ONE acquire fence: single cache invalidate per block per diagonal
            __builtin_amdgcn_fence(__ATOMIC_ACQUIRE, "agent");
        }
        __syncthreads();
    }
}

// ---------- final linear: out[b][T][51] = Wlin @ h3 + b ----------
__global__ __launch_bounds__(256) void final_gemm(
    const f16* __restrict__ A, const f16* __restrict__ B, float* __restrict__ C,
    const float* __restrict__ bias1)
{
    const int T  = blockIdx.x;
    const int tid = threadIdx.x;
    const int wv = tid >> 6, l = tid & 63;
    const int K = 512;
    const int mrow0 = wv * 16;
    int4 a[16];
    {
        const f16* ap = A + (size_t)(mrow0 + (l & 15)) * K + ((l >> 4) * 8);
        #pragma unroll
        for (int kt = 0; kt < 16; ++kt) a[kt] = *(const int4*)(ap + kt * 32);
    }
    #pragma unroll
    for (int nt = 0; nt < 4; ++nt) {
        const int bcol = nt * 16 + (l & 15);
        const f16* bp = B + ((size_t)bcol * SEQ + T) * K + ((l >> 4) * 8);
        f32x4 acc = {0.f, 0.f, 0.f, 0.f};
        #pragma unroll
        for (int kt = 0; kt < 16; ++kt)
            acc = MFMA(a[kt], *(const int4*)(bp + kt * 32), acc);
        #pragma unroll
        for (int e = 0; e < 4; ++e) {
            int row = mrow0 + (l >> 4) * 4 + e;
            if (row < 51)
                C[((size_t)bcol * SEQ + T) * 51 + row] = acc[e] + bias1[row];
        }
    }
}

// ---------- host ----------
extern "C" void kernel_launch(void* const* d_in, const int* in_sizes, int n_in,
                              void* d_out, int out_size, void* d_ws, size_t ws_size,
                              hipStream_t stream)
{
    const float* x     = (const float*)d_in[0];
    const float* w_in  = (const float*)d_in[1];
    const float* W_ih[3] = { (const float*)d_in[2],  (const float*)d_in[6],  (const float*)d_in[10] };
    const float* W_hh[3] = { (const float*)d_in[3],  (const float*)d_in[7],  (const float*)d_in[11] };
    const float* b_ih[3] = { (const float*)d_in[4],  (const float*)d_in[8],  (const float*)d_in[12] };
    const float* b_hh[3] = { (const float*)d_in[5],  (const float*)d_in[9],  (const float*)d_in[13] };
    const float* W_lin = (const float*)d_in[14];
    const float* b_lin = (const float*)d_in[15];
    float* out = (float*)d_out;

    char* ws = (char*)d_ws;
    size_t off = 0;
    auto alloc = [&](size_t bytes) { char* p = ws + off; off += (bytes + 255) & ~(size_t)255; return p; };

    f16* z16 = (f16*)alloc((size_t)NB * SEQ * 128 * 2);
    f16* wih16[3];
    wih16[0] = (f16*)alloc((size_t)GATES * 128 * 2);
    wih16[1] = (f16*)alloc((size_t)GATES * 512 * 2);
    wih16[2] = (f16*)alloc((size_t)GATES * 512 * 2);
    f16* whh16[3];
    for (int i = 0; i < 3; ++i) whh16[i] = (f16*)alloc((size_t)GATES * 512 * 2);
    f16* wlin16 = (f16*)alloc((size_t)64 * 512 * 2);
    f16* Hs16   = (f16*)alloc((size_t)NB * SEQ * 512 * 2);
    f16* Ht     = (f16*)alloc((size_t)3 * 2 * NB * 512 * 2);
    int* barr   = (int*)alloc(192 * 4);

    // prep + conversions
    prep_z<<<(NB * SEQ * 16 + 255) / 256, 256, 0, stream>>>(x, w_in, z16);
    conv16<<<(GATES * 128 + 255) / 256, 256, 0, stream>>>(W_ih[0], wih16[0], GATES, 102, GATES, 128);
    conv16<<<(GATES * 512 + 255) / 256, 256, 0, stream>>>(W_ih[1], wih16[1], GATES, 512, GATES, 512);
    conv16<<<(GATES * 512 + 255) / 256, 256, 0, stream>>>(W_ih[2], wih16[2], GATES, 512, GATES, 512);
    for (int i = 0; i < 3; ++i)
        conv16<<<(GATES * 512 + 255) / 256, 256, 0, stream>>>(W_hh[i], whh16[i], GATES, 512, GATES, 512);
    conv16<<<(64 * 512 + 255) / 256, 256, 0, stream>>>(W_lin, wlin16, 51, 512, 64, 512);
    hipMemsetAsync(Ht, 0, (size_t)3 * 2 * NB * 512 * 2, stream);
    hipMemsetAsync(barr, 0, 192 * 4, stream);

    // fused 3-layer recurrence (single dispatch, 192 co-resident blocks)
    lstm_fused<<<192, 512, 0, stream>>>(
        z16, wih16[0], wih16[1], wih16[2], whh16[0], whh16[1], whh16[2],
        b_ih[0], b_hh[0], b_ih[1], b_hh[1], b_ih[2], b_hh[2],
        Ht, Hs16, barr);

    // final linear
    final_gemm<<<SEQ, 256, 0, stream>>>(wlin16, Hs16, out, b_lin);
}